// Round 1
// baseline (191.301 us; speedup 1.0000x reference)
//
#include <hip/hip_runtime.h>
#include <math.h>

#define EMBED 512
#define HID 16
#define BATCHN 4
#define SEQ 1024
#define ROWS (BATCHN * SEQ)

__device__ __forceinline__ float fast_tanh(float x) {
    float ax = fabsf(x);
    float e = __expf(2.0f * ax);              // e^{2|x|}; inf for large -> r = 1
    float r = 1.0f - __fdividef(2.0f, e + 1.0f);
    return copysignf(r, x);
}

// ---------------- Kernel 1: fold W1 into Wq/Wk ----------------
// WcT[e*32 + h2], h2 in [0,16): Wc_a[h,e] = sum_f W1[h,f]*Wq[f,e]
//                h2 in [16,32): Wc_b[h,e] = sum_f W1[h,512+f]*Wk[f,e]
__global__ __launch_bounds__(256) void wc_kernel(
    const float* __restrict__ Wq, const float* __restrict__ Wk,
    const float* __restrict__ W1, float* __restrict__ WcT)
{
    __shared__ float w1s[EMBED];
    int h2 = blockIdx.x;              // 0..31
    int ab = h2 >> 4, h = h2 & 15;
    const float* Wmat = ab ? Wk : Wq;
    const float* w1row = W1 + (size_t)h * (2 * EMBED) + ab * EMBED;
    int t = threadIdx.x;
    for (int f = t; f < EMBED; f += 256) w1s[f] = w1row[f];
    __syncthreads();
    float acc0 = 0.f, acc1 = 0.f;
    int e0 = t, e1 = t + 256;
    for (int f = 0; f < EMBED; ++f) {
        float w = w1s[f];
        acc0 += w * Wmat[(size_t)f * EMBED + e0];
        acc1 += w * Wmat[(size_t)f * EMBED + e1];
    }
    WcT[(size_t)e0 * 32 + h2] = acc0;
    WcT[(size_t)e1 * 32 + h2] = acc1;
}

// ---------------- Kernel 2: A = x@Wc_a^T + b1, B = x@Wc_b^T ----------------
__global__ __launch_bounds__(256) void ab_kernel(
    const float* __restrict__ x, const float* __restrict__ WcT,
    const float* __restrict__ b1,
    float* __restrict__ A, float* __restrict__ Bm)
{
    __shared__ float xs[8][EMBED];
    int t = threadIdx.x;
    int s0 = blockIdx.x * 8;
    #pragma unroll
    for (int i = 0; i < 4; ++i) {
        int idx = t + i * 256;        // float4 index 0..1023
        int row = idx >> 7;           // /128
        int c4 = idx & 127;
        float4 vv = *(const float4*)(x + (size_t)(s0 + row) * EMBED + c4 * 4);
        *(float4*)&xs[row][c4 * 4] = vv;
    }
    __syncthreads();
    int r = t >> 5, h2 = t & 31;
    const float* xr = xs[r];
    float acc = 0.f;
    for (int k = 0; k < EMBED; ++k)
        acc += xr[k] * WcT[(size_t)k * 32 + h2];
    int s = s0 + r;
    if (h2 < HID) A[(size_t)s * HID + h2] = acc + b1[h2];
    else          Bm[(size_t)s * HID + (h2 - 16)] = acc;
}

// ---------------- Kernel 3: V = x @ Wv^T (64x64x16 fp32 tile) ----------------
__global__ __launch_bounds__(256) void v_kernel(
    const float* __restrict__ x, const float* __restrict__ Wv,
    float* __restrict__ V)
{
    __shared__ float As[16][64];
    __shared__ float Bs[16][64];
    int t = threadIdx.x;
    int ty = t >> 4, tx = t & 15;
    int lm = t >> 2, lq = t & 3;
    int m0 = blockIdx.y * 64, n0 = blockIdx.x * 64;
    float c[4][4] = {};
    for (int k0 = 0; k0 < EMBED; k0 += 16) {
        float4 av = *(const float4*)(x  + (size_t)(m0 + lm) * EMBED + k0 + lq * 4);
        float4 bv = *(const float4*)(Wv + (size_t)(n0 + lm) * EMBED + k0 + lq * 4);
        As[lq*4+0][lm] = av.x; As[lq*4+1][lm] = av.y; As[lq*4+2][lm] = av.z; As[lq*4+3][lm] = av.w;
        Bs[lq*4+0][lm] = bv.x; Bs[lq*4+1][lm] = bv.y; Bs[lq*4+2][lm] = bv.z; Bs[lq*4+3][lm] = bv.w;
        __syncthreads();
        #pragma unroll
        for (int k = 0; k < 16; ++k) {
            float4 a = *(const float4*)&As[k][ty * 4];
            float4 b = *(const float4*)&Bs[k][tx * 4];
            c[0][0] += a.x*b.x; c[0][1] += a.x*b.y; c[0][2] += a.x*b.z; c[0][3] += a.x*b.w;
            c[1][0] += a.y*b.x; c[1][1] += a.y*b.y; c[1][2] += a.y*b.z; c[1][3] += a.y*b.w;
            c[2][0] += a.z*b.x; c[2][1] += a.z*b.y; c[2][2] += a.z*b.z; c[2][3] += a.z*b.w;
            c[3][0] += a.w*b.x; c[3][1] += a.w*b.y; c[3][2] += a.w*b.z; c[3][3] += a.w*b.w;
        }
        __syncthreads();
    }
    #pragma unroll
    for (int i = 0; i < 4; ++i) {
        float4 o = make_float4(c[i][0], c[i][1], c[i][2], c[i][3]);
        *(float4*)(V + (size_t)(m0 + ty * 4 + i) * EMBED + n0 + tx * 4) = o;
    }
}

// ---------------- Kernel 4: logits + softmax -> attn ----------------
__global__ __launch_bounds__(256) void attn_kernel(
    const float* __restrict__ A, const float* __restrict__ Bm,
    const float* __restrict__ w2, float* __restrict__ attn)
{
    __shared__ float redm[4], reds[4];
    int blk = blockIdx.x;
    int b = blk >> 10, i = blk & 1023;
    int t = threadIdx.x;
    float a[HID], w[HID];
    const float* Ar = A + (size_t)(b * SEQ + i) * HID;
    #pragma unroll
    for (int h = 0; h < HID; ++h) { a[h] = Ar[h]; w[h] = w2[h]; }
    const float* Bb = Bm + (size_t)b * SEQ * HID;
    float lg[4];
    #pragma unroll
    for (int c = 0; c < 4; ++c) {
        const float* Br = Bb + (size_t)(t + c * 256) * HID;
        float4 q0 = *(const float4*)(Br);
        float4 q1 = *(const float4*)(Br + 4);
        float4 q2 = *(const float4*)(Br + 8);
        float4 q3 = *(const float4*)(Br + 12);
        float bh[HID] = {q0.x,q0.y,q0.z,q0.w, q1.x,q1.y,q1.z,q1.w,
                         q2.x,q2.y,q2.z,q2.w, q3.x,q3.y,q3.z,q3.w};
        float s = 0.f;
        #pragma unroll
        for (int h = 0; h < HID; ++h)
            s += w[h] * fast_tanh(a[h] + bh[h]);
        lg[c] = s;   // b2 dropped: softmax is shift-invariant
    }
    float m = fmaxf(fmaxf(lg[0], lg[1]), fmaxf(lg[2], lg[3]));
    #pragma unroll
    for (int o = 32; o > 0; o >>= 1) m = fmaxf(m, __shfl_xor(m, o));
    if ((t & 63) == 0) redm[t >> 6] = m;
    __syncthreads();
    m = fmaxf(fmaxf(redm[0], redm[1]), fmaxf(redm[2], redm[3]));
    float p[4], sum = 0.f;
    #pragma unroll
    for (int c = 0; c < 4; ++c) { p[c] = __expf(lg[c] - m); sum += p[c]; }
    #pragma unroll
    for (int o = 32; o > 0; o >>= 1) sum += __shfl_xor(sum, o);
    if ((t & 63) == 0) reds[t >> 6] = sum;
    __syncthreads();
    sum = reds[0] + reds[1] + reds[2] + reds[3];
    float inv = __fdividef(1.0f, sum);
    float* orow = attn + (size_t)(b * SEQ + i) * SEQ;
    #pragma unroll
    for (int c = 0; c < 4; ++c) orow[t + c * 256] = p[c] * inv;
}

// ---------------- Kernel 5: out = attn @ V (per batch) ----------------
__global__ __launch_bounds__(256) void pv_kernel(
    const float* __restrict__ attn, const float* __restrict__ V,
    float* __restrict__ out)
{
    __shared__ float As[16][64];
    __shared__ float Bs[16][64];
    int t = threadIdx.x;
    int ty = t >> 4, tx = t & 15;
    int lm = t >> 2, lq = t & 3;
    int lk = t >> 4, ln = t & 15;
    int b = blockIdx.z;
    int m0 = blockIdx.y * 64, n0 = blockIdx.x * 64;
    const float* Ab = attn + (size_t)b * SEQ * SEQ;
    const float* Vb = V + (size_t)b * SEQ * EMBED;
    float c[4][4] = {};
    for (int k0 = 0; k0 < SEQ; k0 += 16) {
        float4 av = *(const float4*)(Ab + (size_t)(m0 + lm) * SEQ + k0 + lq * 4);
        float4 bv = *(const float4*)(Vb + (size_t)(k0 + lk) * EMBED + n0 + ln * 4);
        As[lq*4+0][lm] = av.x; As[lq*4+1][lm] = av.y; As[lq*4+2][lm] = av.z; As[lq*4+3][lm] = av.w;
        *(float4*)&Bs[lk][ln * 4] = bv;
        __syncthreads();
        #pragma unroll
        for (int k = 0; k < 16; ++k) {
            float4 a = *(const float4*)&As[k][ty * 4];
            float4 b = *(const float4*)&Bs[k][tx * 4];
            c[0][0] += a.x*b.x; c[0][1] += a.x*b.y; c[0][2] += a.x*b.z; c[0][3] += a.x*b.w;
            c[1][0] += a.y*b.x; c[1][1] += a.y*b.y; c[1][2] += a.y*b.z; c[1][3] += a.y*b.w;
            c[2][0] += a.z*b.x; c[2][1] += a.z*b.y; c[2][2] += a.z*b.z; c[2][3] += a.z*b.w;
            c[3][0] += a.w*b.x; c[3][1] += a.w*b.y; c[3][2] += a.w*b.z; c[3][3] += a.w*b.w;
        }
        __syncthreads();
    }
    #pragma unroll
    for (int i = 0; i < 4; ++i) {
        float4 o = make_float4(c[i][0], c[i][1], c[i][2], c[i][3]);
        *(float4*)(out + (size_t)(b * SEQ + m0 + ty * 4 + i) * EMBED + n0 + tx * 4) = o;
    }
}

extern "C" void kernel_launch(void* const* d_in, const int* in_sizes, int n_in,
                              void* d_out, int out_size, void* d_ws, size_t ws_size,
                              hipStream_t stream) {
    const float* x  = (const float*)d_in[0];
    const float* Wq = (const float*)d_in[1];
    const float* Wk = (const float*)d_in[2];
    const float* Wv = (const float*)d_in[3];
    const float* W1 = (const float*)d_in[4];
    const float* b1 = (const float*)d_in[5];
    const float* w2 = (const float*)d_in[6];
    // d_in[7] = b2: softmax shift-invariant, unused.

    float* ws   = (float*)d_ws;
    float* WcT  = ws;                    // 512*32        = 16384 floats
    float* A    = WcT + 16384;           // 4096*16       = 65536
    float* Bm   = A + 65536;             // 4096*16       = 65536
    float* V    = Bm + 65536;            // 4096*512      = 2097152
    float* attn = V + 2097152;           // 4*1024*1024   = 4194304
    float* out  = (float*)d_out;

    hipLaunchKernelGGL(wc_kernel, dim3(32), dim3(256), 0, stream, Wq, Wk, W1, WcT);
    hipLaunchKernelGGL(ab_kernel, dim3(512), dim3(256), 0, stream, x, WcT, b1, A, Bm);
    hipLaunchKernelGGL(v_kernel, dim3(8, 64), dim3(256), 0, stream, x, Wv, V);
    hipLaunchKernelGGL(attn_kernel, dim3(4096), dim3(256), 0, stream, A, Bm, w2, attn);
    hipLaunchKernelGGL(pv_kernel, dim3(8, 16, 4), dim3(256), 0, stream, attn, V, out);
}

// Round 2
// 123.709 us; speedup vs baseline: 1.5464x; 1.5464x over previous
//
#include <hip/hip_runtime.h>
#include <math.h>
#include <stdint.h>

#define EMBED 512
#define HID 16
#define SEQ 1024

typedef unsigned short u16;
typedef __attribute__((ext_vector_type(8))) __bf16 bf16x8;
typedef __attribute__((ext_vector_type(4))) float f32x4;

__device__ __forceinline__ u16 f2bf(float f) {
    unsigned u = __float_as_uint(f);
    unsigned r = (u + 0x7FFFu + ((u >> 16) & 1u)) >> 16;   // RNE
    return (u16)r;
}
__device__ __forceinline__ float bf2f(u16 h) {
    return __uint_as_float(((unsigned)h) << 16);
}

__device__ __forceinline__ float fast_tanh(float x) {
    float ax = fabsf(x);
    float e = __expf(2.0f * ax);
    float r = 1.0f - __fdividef(2.0f, e + 1.0f);
    return copysignf(r, x);
}

// ---------------- Kernel 1: fold W1 into Wq/Wk ----------------
__global__ __launch_bounds__(256) void wc_kernel(
    const float* __restrict__ Wq, const float* __restrict__ Wk,
    const float* __restrict__ W1, float* __restrict__ WcT)
{
    __shared__ float w1s[EMBED];
    int h2 = blockIdx.x;              // 0..31
    int ab = h2 >> 4, h = h2 & 15;
    const float* Wmat = ab ? Wk : Wq;
    const float* w1row = W1 + (size_t)h * (2 * EMBED) + ab * EMBED;
    int t = threadIdx.x;
    for (int f = t; f < EMBED; f += 256) w1s[f] = w1row[f];
    __syncthreads();
    float acc0 = 0.f, acc1 = 0.f;
    int e0 = t, e1 = t + 256;
    for (int f = 0; f < EMBED; ++f) {
        float w = w1s[f];
        acc0 += w * Wmat[(size_t)f * EMBED + e0];
        acc1 += w * Wmat[(size_t)f * EMBED + e1];
    }
    WcT[(size_t)e0 * 32 + h2] = acc0;
    WcT[(size_t)e1 * 32 + h2] = acc1;
}

// ---------------- Kernel 2: A = x@Wc_a^T + b1, B = x@Wc_b^T ----------------
__global__ __launch_bounds__(256) void ab_kernel(
    const float* __restrict__ x, const float* __restrict__ WcT,
    const float* __restrict__ b1,
    float* __restrict__ A, float* __restrict__ Bm)
{
    __shared__ float xs[8][EMBED];
    __shared__ float wcs[EMBED * 32];
    int t = threadIdx.x;
    int s0 = blockIdx.x * 8;
    #pragma unroll
    for (int i = 0; i < 4; ++i) {
        int idx = t + i * 256;
        int row = idx >> 7, c4 = idx & 127;
        float4 vv = *(const float4*)(x + (size_t)(s0 + row) * EMBED + c4 * 4);
        *(float4*)&xs[row][c4 * 4] = vv;
    }
    #pragma unroll
    for (int i = 0; i < 16; ++i) {
        int idx = t + i * 256;
        ((float4*)wcs)[idx] = ((const float4*)WcT)[idx];
    }
    __syncthreads();
    int r = t >> 5, h2 = t & 31;
    const float* xr = xs[r];
    float acc = 0.f;
    #pragma unroll 8
    for (int k = 0; k < EMBED; ++k)
        acc += xr[k] * wcs[k * 32 + h2];
    int s = s0 + r;
    if (h2 < HID) A[(size_t)s * HID + h2] = acc + b1[h2];
    else          Bm[(size_t)s * HID + (h2 - 16)] = acc;
}

// ---------------- Kernel 3: split fp32 -> bf16 hi/lo ----------------
__global__ __launch_bounds__(256) void split_kernel(
    const float* __restrict__ in, u16* __restrict__ hi, u16* __restrict__ lo, int n4)
{
    int i = blockIdx.x * 256 + threadIdx.x;
    if (i >= n4) return;
    float4 v = ((const float4*)in)[i];
    u16 h0 = f2bf(v.x), h1 = f2bf(v.y), h2 = f2bf(v.z), h3 = f2bf(v.w);
    u16 l0 = f2bf(v.x - bf2f(h0)), l1 = f2bf(v.y - bf2f(h1));
    u16 l2 = f2bf(v.z - bf2f(h2)), l3 = f2bf(v.w - bf2f(h3));
    ((ushort4*)hi)[i] = make_ushort4(h0, h1, h2, h3);
    ((ushort4*)lo)[i] = make_ushort4(l0, l1, l2, l3);
}

// ---------------- MFMA GEMM: C[M][N] = A[M][K] * B[N][K]^T (split bf16) ----------------
// LDS tile: 64 rows x 64 k (128B rows), XOR-swizzled slot = s ^ (row&7).
__device__ __forceinline__ void stage64(const u16* src, int ld, int kb0,
                                        u16* ldsb, int t)
{
    #pragma unroll
    for (int i = 0; i < 2; ++i) {
        int row  = i * 32 + (t >> 3);
        int colb = (((t & 7) ^ ((t >> 3) & 7)) << 4);
        const char* g = (const char*)src + (size_t)row * ((size_t)ld * 2) + kb0 + colb;
        char* l = (char*)ldsb + i * 4096 + ((t >> 6) << 10);
        __builtin_amdgcn_global_load_lds(
            reinterpret_cast<const __attribute__((address_space(1))) unsigned int*>(
                reinterpret_cast<uintptr_t>(g)),
            reinterpret_cast<__attribute__((address_space(3))) unsigned int*>(
                reinterpret_cast<uintptr_t>(l)),
            16, 0, 0);
    }
}

__device__ __forceinline__ bf16x8 ldfrag(const u16* ldsb, int r, int s) {
    return *(const bf16x8*)((const char*)ldsb + r * 128 + (((s ^ (r & 7))) << 4));
}

template<int MODE>  // 0: split-bf16 output (VT), 1: fp32 output (out)
__global__ __launch_bounds__(256, 2) void mfma_gemm(
    const u16* __restrict__ Ah, const u16* __restrict__ Al, int lda,
    const u16* __restrict__ Bh, const u16* __restrict__ Bl, int ldb,
    int nkt, size_t batA, size_t batB,
    float* __restrict__ outF, u16* __restrict__ outH, u16* __restrict__ outL,
    int ldc)
{
    __shared__ __attribute__((aligned(16))) u16 lds[16384];   // 32 KB
    u16* lAh = lds;
    u16* lAl = lds + 4096;
    u16* lBh = lds + 8192;
    u16* lBl = lds + 12288;
    int t = threadIdx.x;
    int l = t & 63, wid = t >> 6;
    int wm = (wid >> 1) * 32, wn = (wid & 1) * 32;
    int m0 = blockIdx.y * 64, n0 = blockIdx.x * 64;
    size_t zb = blockIdx.z;
    const u16* pAh = Ah + zb * batA + (size_t)m0 * lda;
    const u16* pAl = Al + zb * batA + (size_t)m0 * lda;
    const u16* pBh = Bh + zb * batB + (size_t)n0 * ldb;
    const u16* pBl = Bl + zb * batB + (size_t)n0 * ldb;

    f32x4 acc[2][2] = {};
    for (int kt = 0; kt < nkt; ++kt) {
        int kb0 = kt << 7;
        stage64(pAh, lda, kb0, lAh, t);
        stage64(pAl, lda, kb0, lAl, t);
        stage64(pBh, ldb, kb0, lBh, t);
        stage64(pBl, ldb, kb0, lBl, t);
        __syncthreads();
        #pragma unroll
        for (int kk = 0; kk < 2; ++kk) {
            int sbase = (kk << 2) + (l >> 4);
            bf16x8 ah[2], al_[2], bh[2], bl_[2];
            #pragma unroll
            for (int mf = 0; mf < 2; ++mf) {
                int r = wm + mf * 16 + (l & 15);
                ah[mf]  = ldfrag(lAh, r, sbase);
                al_[mf] = ldfrag(lAl, r, sbase);
            }
            #pragma unroll
            for (int nf = 0; nf < 2; ++nf) {
                int r = wn + nf * 16 + (l & 15);
                bh[nf]  = ldfrag(lBh, r, sbase);
                bl_[nf] = ldfrag(lBl, r, sbase);
            }
            #pragma unroll
            for (int mf = 0; mf < 2; ++mf)
                #pragma unroll
                for (int nf = 0; nf < 2; ++nf) {
                    acc[mf][nf] = __builtin_amdgcn_mfma_f32_16x16x32_bf16(ah[mf],  bh[nf],  acc[mf][nf], 0, 0, 0);
                    acc[mf][nf] = __builtin_amdgcn_mfma_f32_16x16x32_bf16(ah[mf],  bl_[nf], acc[mf][nf], 0, 0, 0);
                    acc[mf][nf] = __builtin_amdgcn_mfma_f32_16x16x32_bf16(al_[mf], bh[nf],  acc[mf][nf], 0, 0, 0);
                }
        }
        __syncthreads();
    }
    // epilogue: C row=(l>>4)*4+r (M-dim), col=l&15 (N-dim)  [m89-verified]
    int cr = (l >> 4) << 2;
    int cc = l & 15;
    #pragma unroll
    for (int mf = 0; mf < 2; ++mf)
        #pragma unroll
        for (int nf = 0; nf < 2; ++nf)
            #pragma unroll
            for (int r = 0; r < 4; ++r) {
                int row = m0 + wm + mf * 16 + cr + r;
                int col = n0 + wn + nf * 16 + cc;
                float v = acc[mf][nf][r];
                if (MODE == 0) {
                    u16 h = f2bf(v);
                    outH[(size_t)row * ldc + col] = h;
                    outL[(size_t)row * ldc + col] = f2bf(v - bf2f(h));
                } else {
                    outF[zb * ((size_t)SEQ * EMBED) + (size_t)row * ldc + col] = v;
                }
            }
}

// ---------------- Kernel: logits + softmax -> p (bf16 hi/lo, normalized) ----------------
__global__ __launch_bounds__(256) void attn_kernel(
    const float* __restrict__ A, const float* __restrict__ Bm,
    const float* __restrict__ w2, u16* __restrict__ p_hi, u16* __restrict__ p_lo)
{
    __shared__ float redm[4], reds[4];
    int blk = blockIdx.x;
    int b = blk >> 10, i = blk & 1023;
    int t = threadIdx.x;
    float a[HID], w[HID];
    const float* Ar = A + (size_t)(b * SEQ + i) * HID;
    #pragma unroll
    for (int h = 0; h < HID; ++h) { a[h] = Ar[h]; w[h] = w2[h]; }
    const float* Bb = Bm + (size_t)b * SEQ * HID;
    float lg[4];
    #pragma unroll
    for (int c = 0; c < 4; ++c) {
        const float* Br = Bb + (size_t)(t + c * 256) * HID;
        float4 q0 = *(const float4*)(Br);
        float4 q1 = *(const float4*)(Br + 4);
        float4 q2 = *(const float4*)(Br + 8);
        float4 q3 = *(const float4*)(Br + 12);
        float bh[HID] = {q0.x,q0.y,q0.z,q0.w, q1.x,q1.y,q1.z,q1.w,
                         q2.x,q2.y,q2.z,q2.w, q3.x,q3.y,q3.z,q3.w};
        float s = 0.f;
        #pragma unroll
        for (int h = 0; h < HID; ++h)
            s += w[h] * fast_tanh(a[h] + bh[h]);
        lg[c] = s;   // b2 dropped: softmax shift-invariant
    }
    float m = fmaxf(fmaxf(lg[0], lg[1]), fmaxf(lg[2], lg[3]));
    #pragma unroll
    for (int o = 32; o > 0; o >>= 1) m = fmaxf(m, __shfl_xor(m, o));
    if ((t & 63) == 0) redm[t >> 6] = m;
    __syncthreads();
    m = fmaxf(fmaxf(redm[0], redm[1]), fmaxf(redm[2], redm[3]));
    float p[4], sum = 0.f;
    #pragma unroll
    for (int c = 0; c < 4; ++c) { p[c] = __expf(lg[c] - m); sum += p[c]; }
    #pragma unroll
    for (int o = 32; o > 0; o >>= 1) sum += __shfl_xor(sum, o);
    if ((t & 63) == 0) reds[t >> 6] = sum;
    __syncthreads();
    sum = reds[0] + reds[1] + reds[2] + reds[3];
    float inv = __fdividef(1.0f, sum);
    size_t base = (size_t)(b * SEQ + i) * SEQ;
    #pragma unroll
    for (int c = 0; c < 4; ++c) {
        float pv = p[c] * inv;
        u16 h = f2bf(pv);
        p_hi[base + t + c * 256] = h;
        p_lo[base + t + c * 256] = f2bf(pv - bf2f(h));
    }
}

extern "C" void kernel_launch(void* const* d_in, const int* in_sizes, int n_in,
                              void* d_out, int out_size, void* d_ws, size_t ws_size,
                              hipStream_t stream) {
    const float* x  = (const float*)d_in[0];
    const float* Wq = (const float*)d_in[1];
    const float* Wk = (const float*)d_in[2];
    const float* Wv = (const float*)d_in[3];
    const float* W1 = (const float*)d_in[4];
    const float* b1 = (const float*)d_in[5];
    const float* w2 = (const float*)d_in[6];
    // d_in[7] = b2: softmax shift-invariant, unused.

    char* ws = (char*)d_ws;
    // byte offsets — total 25,755,648 B (== round-1 proven footprint)
    float* WcT   = (float*)(ws + 0);          //    65,536 B
    float* A     = (float*)(ws + 65536);      //   262,144 B
    float* Bm    = (float*)(ws + 327680);     //   262,144 B
    u16*   VT_hi = (u16*)(ws + 589824);       // 4,194,304 B (512 x 4096)
    u16*   VT_lo = (u16*)(ws + 4784128);      // 4,194,304 B
    u16*   Xreg  = (u16*)(ws + 8978432);      // 8,388,608 B: x_hi|x_lo, later p_lo
    u16*   Preg  = (u16*)(ws + 17367040);     // 8,388,608 B: wv_hi|wv_lo, later p_hi
    u16* x_hi  = Xreg;
    u16* x_lo  = Xreg + 2097152;
    u16* p_lo  = Xreg;
    u16* wv_hi = Preg;
    u16* wv_lo = Preg + 262144;
    u16* p_hi  = Preg;
    float* out = (float*)d_out;

    hipLaunchKernelGGL(wc_kernel, dim3(32), dim3(256), 0, stream, Wq, Wk, W1, WcT);
    hipLaunchKernelGGL(ab_kernel, dim3(512), dim3(256), 0, stream, x, WcT, b1, A, Bm);
    hipLaunchKernelGGL(split_kernel, dim3(2048), dim3(256), 0, stream, x, x_hi, x_lo, 524288);
    hipLaunchKernelGGL(split_kernel, dim3(256), dim3(256), 0, stream, Wv, wv_hi, wv_lo, 65536);
    // VT[512][4096] = Wv(rows) x x(rows)^T  -> V transposed, per-batch slice via k-offset later
    hipLaunchKernelGGL((mfma_gemm<0>), dim3(64, 8, 1), dim3(256), 0, stream,
                       wv_hi, wv_lo, EMBED, x_hi, x_lo, EMBED,
                       8, (size_t)0, (size_t)0, (float*)nullptr, VT_hi, VT_lo, 4096);
    // p (overwrites wv/x regions — stream-ordered after vgemm)
    hipLaunchKernelGGL(attn_kernel, dim3(4096), dim3(256), 0, stream, A, Bm, w2, p_hi, p_lo);
    // out[b*1024+m][n] = sum_k p[b][m][k] * VT[n][b*1024+k]
    hipLaunchKernelGGL((mfma_gemm<1>), dim3(8, 16, 4), dim3(256), 0, stream,
                       p_hi, p_lo, SEQ, VT_hi, VT_lo, 4096,
                       16, (size_t)SEQ * SEQ, (size_t)SEQ, out, (u16*)nullptr, (u16*)nullptr, EMBED);
}

// Round 3
// 103.592 us; speedup vs baseline: 1.8467x; 1.1942x over previous
//
#include <hip/hip_runtime.h>
#include <math.h>
#include <stdint.h>

#define EMBED 512
#define HID 16
#define SEQ 1024

typedef unsigned short u16;
typedef __attribute__((ext_vector_type(8))) __bf16 bf16x8;
typedef __attribute__((ext_vector_type(4))) float f32x4;

__device__ __forceinline__ u16 f2bf(float f) {
    unsigned u = __float_as_uint(f);
    unsigned r = (u + 0x7FFFu + ((u >> 16) & 1u)) >> 16;   // RNE
    return (u16)r;
}
__device__ __forceinline__ float bf2f(u16 h) {
    return __uint_as_float(((unsigned)h) << 16);
}

// ---------------- Kernel 1: fold W1 into Wq/Wk ----------------
__global__ __launch_bounds__(256) void wc_kernel(
    const float* __restrict__ Wq, const float* __restrict__ Wk,
    const float* __restrict__ W1, float* __restrict__ WcT)
{
    __shared__ float w1s[EMBED];
    int h2 = blockIdx.x;              // 0..31
    int ab = h2 >> 4, h = h2 & 15;
    const float* Wmat = ab ? Wk : Wq;
    const float* w1row = W1 + (size_t)h * (2 * EMBED) + ab * EMBED;
    int t = threadIdx.x;
    for (int f = t; f < EMBED; f += 256) w1s[f] = w1row[f];
    __syncthreads();
    float acc0 = 0.f, acc1 = 0.f;
    int e0 = t, e1 = t + 256;
    for (int f = 0; f < EMBED; ++f) {
        float w = w1s[f];
        acc0 += w * Wmat[(size_t)f * EMBED + e0];
        acc1 += w * Wmat[(size_t)f * EMBED + e1];
    }
    WcT[(size_t)e0 * 32 + h2] = acc0;
    WcT[(size_t)e1 * 32 + h2] = acc1;
}

// ---------------- Kernel 2: A = x@Wc_a^T + b1, B = x@Wc_b^T ----------------
__global__ __launch_bounds__(256) void ab_kernel(
    const float* __restrict__ x, const float* __restrict__ WcT,
    const float* __restrict__ b1,
    float* __restrict__ A, float* __restrict__ Bm)
{
    __shared__ float xs[8][EMBED];
    __shared__ float wcs[EMBED * 32];
    int t = threadIdx.x;
    int s0 = blockIdx.x * 8;
    #pragma unroll
    for (int i = 0; i < 4; ++i) {
        int idx = t + i * 256;
        int row = idx >> 7, c4 = idx & 127;
        float4 vv = *(const float4*)(x + (size_t)(s0 + row) * EMBED + c4 * 4);
        *(float4*)&xs[row][c4 * 4] = vv;
    }
    #pragma unroll
    for (int i = 0; i < 16; ++i) {
        int idx = t + i * 256;
        ((float4*)wcs)[idx] = ((const float4*)WcT)[idx];
    }
    __syncthreads();
    int r = t >> 5, h2 = t & 31;
    const float* xr = xs[r];
    float acc = 0.f;
    #pragma unroll 8
    for (int k = 0; k < EMBED; ++k)
        acc += xr[k] * wcs[k * 32 + h2];
    int s = s0 + r;
    if (h2 < HID) A[(size_t)s * HID + h2] = acc + b1[h2];
    else          Bm[(size_t)s * HID + (h2 - 16)] = acc;
}

// ---------------- Kernel 3: split fp32 -> bf16 hi/lo ----------------
__global__ __launch_bounds__(256) void split_kernel(
    const float* __restrict__ in, u16* __restrict__ hi, u16* __restrict__ lo, int n4)
{
    int i = blockIdx.x * 256 + threadIdx.x;
    if (i >= n4) return;
    float4 v = ((const float4*)in)[i];
    u16 h0 = f2bf(v.x), h1 = f2bf(v.y), h2 = f2bf(v.z), h3 = f2bf(v.w);
    u16 l0 = f2bf(v.x - bf2f(h0)), l1 = f2bf(v.y - bf2f(h1));
    u16 l2 = f2bf(v.z - bf2f(h2)), l3 = f2bf(v.w - bf2f(h3));
    ((ushort4*)hi)[i] = make_ushort4(h0, h1, h2, h3);
    ((ushort4*)lo)[i] = make_ushort4(l0, l1, l2, l3);
}

// ---------------- MFMA GEMM: C[M][N] = A[M][K] * B[N][K]^T (split bf16) ----------------
// LDS tile: 64 rows x 64 k (128B rows), XOR-swizzled slot = s ^ (row&7).
__device__ __forceinline__ void stage64(const u16* src, int ld, int kb0,
                                        u16* ldsb, int t)
{
    #pragma unroll
    for (int i = 0; i < 2; ++i) {
        int row  = i * 32 + (t >> 3);
        int colb = (((t & 7) ^ ((t >> 3) & 7)) << 4);
        const char* g = (const char*)src + (size_t)row * ((size_t)ld * 2) + kb0 + colb;
        char* l = (char*)ldsb + i * 4096 + ((t >> 6) << 10);
        __builtin_amdgcn_global_load_lds(
            reinterpret_cast<const __attribute__((address_space(1))) unsigned int*>(
                reinterpret_cast<uintptr_t>(g)),
            reinterpret_cast<__attribute__((address_space(3))) unsigned int*>(
                reinterpret_cast<uintptr_t>(l)),
            16, 0, 0);
    }
}

__device__ __forceinline__ bf16x8 ldfrag(const u16* ldsb, int r, int s) {
    return *(const bf16x8*)((const char*)ldsb + r * 128 + (((s ^ (r & 7))) << 4));
}

template<int MODE>  // 0: split-bf16 output (VT), 1: fp32 output (out)
__global__ __launch_bounds__(256, 2) void mfma_gemm(
    const u16* __restrict__ Ah, const u16* __restrict__ Al, int lda,
    const u16* __restrict__ Bh, const u16* __restrict__ Bl, int ldb,
    int nkt, size_t batA, size_t batB,
    float* __restrict__ outF, u16* __restrict__ outH, u16* __restrict__ outL,
    int ldc)
{
    __shared__ __attribute__((aligned(16))) u16 lds[16384];   // 32 KB
    u16* lAh = lds;
    u16* lAl = lds + 4096;
    u16* lBh = lds + 8192;
    u16* lBl = lds + 12288;
    int t = threadIdx.x;
    int l = t & 63, wid = t >> 6;
    int wm = (wid >> 1) * 32, wn = (wid & 1) * 32;
    int m0 = blockIdx.y * 64, n0 = blockIdx.x * 64;
    size_t zb = blockIdx.z;
    const u16* pAh = Ah + zb * batA + (size_t)m0 * lda;
    const u16* pAl = Al + zb * batA + (size_t)m0 * lda;
    const u16* pBh = Bh + zb * batB + (size_t)n0 * ldb;
    const u16* pBl = Bl + zb * batB + (size_t)n0 * ldb;

    f32x4 acc[2][2] = {};
    for (int kt = 0; kt < nkt; ++kt) {
        int kb0 = kt << 7;
        stage64(pAh, lda, kb0, lAh, t);
        stage64(pAl, lda, kb0, lAl, t);
        stage64(pBh, ldb, kb0, lBh, t);
        stage64(pBl, ldb, kb0, lBl, t);
        __syncthreads();
        #pragma unroll
        for (int kk = 0; kk < 2; ++kk) {
            int sbase = (kk << 2) + (l >> 4);
            bf16x8 ah[2], al_[2], bh[2], bl_[2];
            #pragma unroll
            for (int mf = 0; mf < 2; ++mf) {
                int r = wm + mf * 16 + (l & 15);
                ah[mf]  = ldfrag(lAh, r, sbase);
                al_[mf] = ldfrag(lAl, r, sbase);
            }
            #pragma unroll
            for (int nf = 0; nf < 2; ++nf) {
                int r = wn + nf * 16 + (l & 15);
                bh[nf]  = ldfrag(lBh, r, sbase);
                bl_[nf] = ldfrag(lBl, r, sbase);
            }
            #pragma unroll
            for (int mf = 0; mf < 2; ++mf)
                #pragma unroll
                for (int nf = 0; nf < 2; ++nf) {
                    acc[mf][nf] = __builtin_amdgcn_mfma_f32_16x16x32_bf16(ah[mf],  bh[nf],  acc[mf][nf], 0, 0, 0);
                    acc[mf][nf] = __builtin_amdgcn_mfma_f32_16x16x32_bf16(ah[mf],  bl_[nf], acc[mf][nf], 0, 0, 0);
                    acc[mf][nf] = __builtin_amdgcn_mfma_f32_16x16x32_bf16(al_[mf], bh[nf],  acc[mf][nf], 0, 0, 0);
                }
        }
        __syncthreads();
    }
    // epilogue: C row=(l>>4)*4+r (M-dim), col=l&15 (N-dim)  [m89-verified]
    int cr = (l >> 4) << 2;
    int cc = l & 15;
    #pragma unroll
    for (int mf = 0; mf < 2; ++mf)
        #pragma unroll
        for (int nf = 0; nf < 2; ++nf)
            #pragma unroll
            for (int r = 0; r < 4; ++r) {
                int row = m0 + wm + mf * 16 + cr + r;
                int col = n0 + wn + nf * 16 + cc;
                float v = acc[mf][nf][r];
                if (MODE == 0) {
                    u16 h = f2bf(v);
                    outH[(size_t)row * ldc + col] = h;
                    outL[(size_t)row * ldc + col] = f2bf(v - bf2f(h));
                } else {
                    outF[zb * ((size_t)SEQ * EMBED) + (size_t)row * ldc + col] = v;
                }
            }
}

// ---------------- Kernel: logits + softmax -> p (bf16 hi/lo, normalized) ----------------
// tanh(x) = 1 - 2/(exp2(K2*x)+1), K2 = 2*log2(e). Handles +-inf without abs/copysign.
// logit = sum_h w[h]*tanh(a[h]+b[h]) = const + sum_h (-2w[h])*rcp(exp2(K2*b[h]+K2*a[h])+1)
// (the const = sum_h w[h] shifts all logits equally -> softmax-invariant -> dropped)
__global__ __launch_bounds__(256) void attn_kernel(
    const float* __restrict__ A, const float* __restrict__ Bm,
    const float* __restrict__ w2, u16* __restrict__ p_hi, u16* __restrict__ p_lo)
{
    const float K2 = 2.8853900817779268f;   // 2*log2(e)
    const float L2E = 1.4426950408889634f;  // log2(e)
    __shared__ float redm[4], reds[4];
    int blk = blockIdx.x;
    int b = blk >> 10, i = blk & 1023;
    int t = threadIdx.x;
    float ak[HID], wm2[HID];
    const float* Ar = A + (size_t)(b * SEQ + i) * HID;
    #pragma unroll
    for (int h = 0; h < HID; ++h) {
        ak[h]  = K2 * Ar[h];
        wm2[h] = -2.0f * w2[h];
    }
    const float* Bb = Bm + (size_t)b * SEQ * HID;

    // software-pipelined: load chunk c+1 while computing chunk c
    float4 qa[4], qb[4];
    {
        const float4* s0 = (const float4*)(Bb + (size_t)t * HID);
        #pragma unroll
        for (int j = 0; j < 4; ++j) qa[j] = s0[j];
    }
    float lg[4];
    #pragma unroll
    for (int c = 0; c < 4; ++c) {
        const float4* cur = (c & 1) ? qb : qa;
        float4* nxt = (c & 1) ? qa : qb;
        if (c < 3) {
            const float4* sn = (const float4*)(Bb + (size_t)(t + (c + 1) * 256) * HID);
            #pragma unroll
            for (int j = 0; j < 4; ++j) nxt[j] = sn[j];
        }
        const float* bh = (const float*)cur;
        float s = 0.f;
        #pragma unroll
        for (int h = 0; h < HID; ++h) {
            float e = __builtin_amdgcn_exp2f(fmaf(K2, bh[h], ak[h]));
            s = fmaf(wm2[h], __builtin_amdgcn_rcpf(e + 1.0f), s);
        }
        lg[c] = s;
    }

    float m = fmaxf(fmaxf(lg[0], lg[1]), fmaxf(lg[2], lg[3]));
    #pragma unroll
    for (int o = 32; o > 0; o >>= 1) m = fmaxf(m, __shfl_xor(m, o));
    if ((t & 63) == 0) redm[t >> 6] = m;
    __syncthreads();
    m = fmaxf(fmaxf(redm[0], redm[1]), fmaxf(redm[2], redm[3]));
    float p[4], sum = 0.f;
    #pragma unroll
    for (int c = 0; c < 4; ++c) {
        p[c] = __builtin_amdgcn_exp2f((lg[c] - m) * L2E);
        sum += p[c];
    }
    #pragma unroll
    for (int o = 32; o > 0; o >>= 1) sum += __shfl_xor(sum, o);
    if ((t & 63) == 0) reds[t >> 6] = sum;
    __syncthreads();
    sum = reds[0] + reds[1] + reds[2] + reds[3];
    float inv = __fdividef(1.0f, sum);
    size_t base = (size_t)(b * SEQ + i) * SEQ;
    #pragma unroll
    for (int c = 0; c < 4; ++c) {
        float pv = p[c] * inv;
        u16 h = f2bf(pv);
        p_hi[base + t + c * 256] = h;
        p_lo[base + t + c * 256] = f2bf(pv - bf2f(h));
    }
}

extern "C" void kernel_launch(void* const* d_in, const int* in_sizes, int n_in,
                              void* d_out, int out_size, void* d_ws, size_t ws_size,
                              hipStream_t stream) {
    const float* x  = (const float*)d_in[0];
    const float* Wq = (const float*)d_in[1];
    const float* Wk = (const float*)d_in[2];
    const float* Wv = (const float*)d_in[3];
    const float* W1 = (const float*)d_in[4];
    const float* b1 = (const float*)d_in[5];
    const float* w2 = (const float*)d_in[6];
    // d_in[7] = b2: softmax shift-invariant, unused.

    char* ws = (char*)d_ws;
    float* WcT   = (float*)(ws + 0);          //    65,536 B
    float* A     = (float*)(ws + 65536);      //   262,144 B
    float* Bm    = (float*)(ws + 327680);     //   262,144 B
    u16*   VT_hi = (u16*)(ws + 589824);       // 4,194,304 B (512 x 4096)
    u16*   VT_lo = (u16*)(ws + 4784128);      // 4,194,304 B
    u16*   Xreg  = (u16*)(ws + 8978432);      // 8,388,608 B: x_hi|x_lo, later p_lo
    u16*   Preg  = (u16*)(ws + 17367040);     // 8,388,608 B: wv_hi|wv_lo, later p_hi
    u16* x_hi  = Xreg;
    u16* x_lo  = Xreg + 2097152;
    u16* p_lo  = Xreg;
    u16* wv_hi = Preg;
    u16* wv_lo = Preg + 262144;
    u16* p_hi  = Preg;
    float* out = (float*)d_out;

    hipLaunchKernelGGL(wc_kernel, dim3(32), dim3(256), 0, stream, Wq, Wk, W1, WcT);
    hipLaunchKernelGGL(ab_kernel, dim3(512), dim3(256), 0, stream, x, WcT, b1, A, Bm);
    hipLaunchKernelGGL(split_kernel, dim3(2048), dim3(256), 0, stream, x, x_hi, x_lo, 524288);
    hipLaunchKernelGGL(split_kernel, dim3(256), dim3(256), 0, stream, Wv, wv_hi, wv_lo, 65536);
    // VT[512][4096] = Wv(rows) x x(rows)^T  -> V transposed
    hipLaunchKernelGGL((mfma_gemm<0>), dim3(64, 8, 1), dim3(256), 0, stream,
                       wv_hi, wv_lo, EMBED, x_hi, x_lo, EMBED,
                       8, (size_t)0, (size_t)0, (float*)nullptr, VT_hi, VT_lo, 4096);
    // p (overwrites wv/x regions — stream-ordered after vgemm)
    hipLaunchKernelGGL(attn_kernel, dim3(4096), dim3(256), 0, stream, A, Bm, w2, p_hi, p_lo);
    // out[b*1024+m][n] = sum_k p[b][m][k] * VT[n][b*1024+k]
    hipLaunchKernelGGL((mfma_gemm<1>), dim3(8, 16, 4), dim3(256), 0, stream,
                       p_hi, p_lo, SEQ, VT_hi, VT_lo, 4096,
                       16, (size_t)SEQ * SEQ, (size_t)SEQ, out, (u16*)nullptr, (u16*)nullptr, EMBED);
}

// Round 4
// 101.251 us; speedup vs baseline: 1.8894x; 1.0231x over previous
//
#include <hip/hip_runtime.h>
#include <math.h>
#include <stdint.h>

#define EMBED 512
#define HID 16
#define SEQ 1024

typedef unsigned short u16;
typedef __attribute__((ext_vector_type(8))) __bf16 bf16x8;
typedef __attribute__((ext_vector_type(4))) float f32x4;

__device__ __forceinline__ u16 f2bf(float f) {
    unsigned u = __float_as_uint(f);
    unsigned r = (u + 0x7FFFu + ((u >> 16) & 1u)) >> 16;   // RNE
    return (u16)r;
}
__device__ __forceinline__ float bf2f(u16 h) {
    return __uint_as_float(((unsigned)h) << 16);
}

// ---------------- Kernel 1: fold W1 into Wq/Wk ----------------
__global__ __launch_bounds__(256) void wc_kernel(
    const float* __restrict__ Wq, const float* __restrict__ Wk,
    const float* __restrict__ W1, float* __restrict__ WcT)
{
    __shared__ float w1s[EMBED];
    int h2 = blockIdx.x;              // 0..31
    int ab = h2 >> 4, h = h2 & 15;
    const float* Wmat = ab ? Wk : Wq;
    const float* w1row = W1 + (size_t)h * (2 * EMBED) + ab * EMBED;
    int t = threadIdx.x;
    for (int f = t; f < EMBED; f += 256) w1s[f] = w1row[f];
    __syncthreads();
    float acc0 = 0.f, acc1 = 0.f;
    int e0 = t, e1 = t + 256;
    for (int f = 0; f < EMBED; ++f) {
        float w = w1s[f];
        acc0 += w * Wmat[(size_t)f * EMBED + e0];
        acc1 += w * Wmat[(size_t)f * EMBED + e1];
    }
    WcT[(size_t)e0 * 32 + h2] = acc0;
    WcT[(size_t)e1 * 32 + h2] = acc1;
}

// ---------------- Kernel 2: A = x@Wc_a^T + b1, B = x@Wc_b^T ----------------
__global__ __launch_bounds__(256) void ab_kernel(
    const float* __restrict__ x, const float* __restrict__ WcT,
    const float* __restrict__ b1,
    float* __restrict__ A, float* __restrict__ Bm)
{
    __shared__ float xs[8][EMBED];
    __shared__ float wcs[EMBED * 32];
    int t = threadIdx.x;
    int s0 = blockIdx.x * 8;
    #pragma unroll
    for (int i = 0; i < 4; ++i) {
        int idx = t + i * 256;
        int row = idx >> 7, c4 = idx & 127;
        float4 vv = *(const float4*)(x + (size_t)(s0 + row) * EMBED + c4 * 4);
        *(float4*)&xs[row][c4 * 4] = vv;
    }
    #pragma unroll
    for (int i = 0; i < 16; ++i) {
        int idx = t + i * 256;
        ((float4*)wcs)[idx] = ((const float4*)WcT)[idx];
    }
    __syncthreads();
    int r = t >> 5, h2 = t & 31;
    const float* xr = xs[r];
    float acc = 0.f;
    #pragma unroll 8
    for (int k = 0; k < EMBED; ++k)
        acc += xr[k] * wcs[k * 32 + h2];
    int s = s0 + r;
    if (h2 < HID) A[(size_t)s * HID + h2] = acc + b1[h2];
    else          Bm[(size_t)s * HID + (h2 - 16)] = acc;
}

// ---------------- Kernel 3: split fp32 -> bf16 hi/lo ----------------
__global__ __launch_bounds__(256) void split_kernel(
    const float* __restrict__ in, u16* __restrict__ hi, u16* __restrict__ lo, int n4)
{
    int i = blockIdx.x * 256 + threadIdx.x;
    if (i >= n4) return;
    float4 v = ((const float4*)in)[i];
    u16 h0 = f2bf(v.x), h1 = f2bf(v.y), h2 = f2bf(v.z), h3 = f2bf(v.w);
    u16 l0 = f2bf(v.x - bf2f(h0)), l1 = f2bf(v.y - bf2f(h1));
    u16 l2 = f2bf(v.z - bf2f(h2)), l3 = f2bf(v.w - bf2f(h3));
    ((ushort4*)hi)[i] = make_ushort4(h0, h1, h2, h3);
    ((ushort4*)lo)[i] = make_ushort4(l0, l1, l2, l3);
}

// ---------------- MFMA GEMM: C[M][N] = A[M][K] * B[N][K]^T (split bf16) ----------------
// LDS tile: 64 rows x 64 k (128B rows), XOR-swizzled slot = s ^ (row&7).
// 2-phase double-buffered: STAGE(next) issued before COMPUTE(cur), one barrier/K-tile.
__device__ __forceinline__ void stage64(const u16* src, int ld, int kb0,
                                        u16* ldsb, int t)
{
    #pragma unroll
    for (int i = 0; i < 2; ++i) {
        int row  = i * 32 + (t >> 3);
        int colb = (((t & 7) ^ ((t >> 3) & 7)) << 4);
        const char* g = (const char*)src + (size_t)row * ((size_t)ld * 2) + kb0 + colb;
        char* l = (char*)ldsb + i * 4096 + ((t >> 6) << 10);
        __builtin_amdgcn_global_load_lds(
            reinterpret_cast<const __attribute__((address_space(1))) unsigned int*>(
                reinterpret_cast<uintptr_t>(g)),
            reinterpret_cast<__attribute__((address_space(3))) unsigned int*>(
                reinterpret_cast<uintptr_t>(l)),
            16, 0, 0);
    }
}

__device__ __forceinline__ bf16x8 ldfrag(const u16* ldsb, int r, int s) {
    return *(const bf16x8*)((const char*)ldsb + r * 128 + (((s ^ (r & 7))) << 4));
}

template<int MODE>  // 0: split-bf16 output (VT), 1: fp32 output (out)
__global__ __launch_bounds__(256, 2) void mfma_gemm(
    const u16* __restrict__ Ah, const u16* __restrict__ Al, int lda,
    const u16* __restrict__ Bh, const u16* __restrict__ Bl, int ldb,
    int nkt, size_t batA, size_t batB,
    float* __restrict__ outF, u16* __restrict__ outH, u16* __restrict__ outL,
    int ldc)
{
    __shared__ __attribute__((aligned(16))) u16 lds[2][16384];   // 2 x 32 KB
    int t = threadIdx.x;
    int l = t & 63, wid = t >> 6;
    int wm = (wid >> 1) * 32, wn = (wid & 1) * 32;
    int m0 = blockIdx.y * 64, n0 = blockIdx.x * 64;
    size_t zb = blockIdx.z;
    const u16* pAh = Ah + zb * batA + (size_t)m0 * lda;
    const u16* pAl = Al + zb * batA + (size_t)m0 * lda;
    const u16* pBh = Bh + zb * batB + (size_t)n0 * ldb;
    const u16* pBl = Bl + zb * batB + (size_t)n0 * ldb;

    f32x4 acc[2][2] = {};

    auto STAGE = [&](int buf, int kt) {
        int kb0 = kt << 7;
        u16* base = lds[buf];
        stage64(pAh, lda, kb0, base,         t);
        stage64(pAl, lda, kb0, base + 4096,  t);
        stage64(pBh, ldb, kb0, base + 8192,  t);
        stage64(pBl, ldb, kb0, base + 12288, t);
    };
    auto COMPUTE = [&](int buf) {
        u16* lAh = lds[buf];
        u16* lAl = lds[buf] + 4096;
        u16* lBh = lds[buf] + 8192;
        u16* lBl = lds[buf] + 12288;
        #pragma unroll
        for (int kk = 0; kk < 2; ++kk) {
            int sbase = (kk << 2) + (l >> 4);
            bf16x8 ah[2], al_[2], bh[2], bl_[2];
            #pragma unroll
            for (int mf = 0; mf < 2; ++mf) {
                int r = wm + mf * 16 + (l & 15);
                ah[mf]  = ldfrag(lAh, r, sbase);
                al_[mf] = ldfrag(lAl, r, sbase);
            }
            #pragma unroll
            for (int nf = 0; nf < 2; ++nf) {
                int r = wn + nf * 16 + (l & 15);
                bh[nf]  = ldfrag(lBh, r, sbase);
                bl_[nf] = ldfrag(lBl, r, sbase);
            }
            #pragma unroll
            for (int mf = 0; mf < 2; ++mf)
                #pragma unroll
                for (int nf = 0; nf < 2; ++nf) {
                    acc[mf][nf] = __builtin_amdgcn_mfma_f32_16x16x32_bf16(ah[mf],  bh[nf],  acc[mf][nf], 0, 0, 0);
                    acc[mf][nf] = __builtin_amdgcn_mfma_f32_16x16x32_bf16(ah[mf],  bl_[nf], acc[mf][nf], 0, 0, 0);
                    acc[mf][nf] = __builtin_amdgcn_mfma_f32_16x16x32_bf16(al_[mf], bh[nf],  acc[mf][nf], 0, 0, 0);
                }
        }
    };

    STAGE(0, 0);
    __syncthreads();                     // drain (syncthreads emits vmcnt(0))
    int cur = 0;
    for (int kt = 0; kt + 1 < nkt; ++kt) {
        STAGE(cur ^ 1, kt + 1);          // prefetch next tile into other buffer
        COMPUTE(cur);                    // MFMA hides the prefetch latency
        __syncthreads();                 // drains vmcnt+lgkmcnt: next tile ready
        cur ^= 1;
    }
    COMPUTE(cur);

    // epilogue: C row=(l>>4)*4+r (M-dim), col=l&15 (N-dim)  [m89-verified]
    int cr = (l >> 4) << 2;
    int cc = l & 15;
    #pragma unroll
    for (int mf = 0; mf < 2; ++mf)
        #pragma unroll
        for (int nf = 0; nf < 2; ++nf)
            #pragma unroll
            for (int r = 0; r < 4; ++r) {
                int row = m0 + wm + mf * 16 + cr + r;
                int col = n0 + wn + nf * 16 + cc;
                float v = acc[mf][nf][r];
                if (MODE == 0) {
                    u16 h = f2bf(v);
                    outH[(size_t)row * ldc + col] = h;
                    outL[(size_t)row * ldc + col] = f2bf(v - bf2f(h));
                } else {
                    outF[zb * ((size_t)SEQ * EMBED) + (size_t)row * ldc + col] = v;
                }
            }
}

// ---------------- Kernel: logits + softmax -> p (bf16 hi/lo, normalized) ----------------
// tanh(x) = 1 - 2/(exp2(K2*x)+1), K2 = 2*log2(e).
// Pairwise rcp: w1*tanh(x1)+w2*tanh(x2) = (w1+w2) - 2*[w1(e2+1)+w2(e1+1)]/[(e1+1)(e2+1)]
// with e_i = exp2(K2*x_i). Constants (sum of w) shift all logits equally -> dropped.
// Per h-pair: 2 exp + 1 rcp (was 2 exp + 2 rcp).
__global__ __launch_bounds__(256) void attn_kernel(
    const float* __restrict__ A, const float* __restrict__ Bm,
    const float* __restrict__ w2, u16* __restrict__ p_hi, u16* __restrict__ p_lo)
{
    const float K2 = 2.8853900817779268f;   // 2*log2(e)
    const float L2E = 1.4426950408889634f;  // log2(e)
    __shared__ float redm[4], reds[4];
    int blk = blockIdx.x;
    int b = blk >> 10, i = blk & 1023;
    int t = threadIdx.x;
    float ak[HID], W1h[8], W2h[8], Wsh[8];
    const float* Ar = A + (size_t)(b * SEQ + i) * HID;
    #pragma unroll
    for (int h = 0; h < HID; ++h) ak[h] = K2 * Ar[h];
    #pragma unroll
    for (int p = 0; p < 8; ++p) {
        float w1 = -2.0f * w2[2 * p], w2_ = -2.0f * w2[2 * p + 1];
        W1h[p] = w1; W2h[p] = w2_; Wsh[p] = w1 + w2_;
    }
    const float* Bb = Bm + (size_t)b * SEQ * HID;

    // all 16 loads issued up-front: one L2 latency, not a 4-deep chain
    float4 q[4][4];
    #pragma unroll
    for (int c = 0; c < 4; ++c) {
        const float4* s0 = (const float4*)(Bb + (size_t)(t + c * 256) * HID);
        #pragma unroll
        for (int j = 0; j < 4; ++j) q[c][j] = s0[j];
    }
    float lg[4];
    #pragma unroll
    for (int c = 0; c < 4; ++c) {
        const float* bh = (const float*)q[c];
        float s = 0.f;
        #pragma unroll
        for (int p = 0; p < 8; ++p) {
            float e1 = __builtin_amdgcn_exp2f(fmaf(K2, bh[2 * p],     ak[2 * p]));
            float e2 = __builtin_amdgcn_exp2f(fmaf(K2, bh[2 * p + 1], ak[2 * p + 1]));
            float d  = fmaf(e1, e2, e1) + e2 + 1.0f;       // (e1+1)(e2+1)
            float n  = fmaf(W1h[p], e2, Wsh[p]);
            n        = fmaf(W2h[p], e1, n);                // W1*e2 + W2*e1 + W1+W2
            s        = fmaf(n, __builtin_amdgcn_rcpf(d), s);
        }
        lg[c] = s;
    }

    float m = fmaxf(fmaxf(lg[0], lg[1]), fmaxf(lg[2], lg[3]));
    #pragma unroll
    for (int o = 32; o > 0; o >>= 1) m = fmaxf(m, __shfl_xor(m, o));
    if ((t & 63) == 0) redm[t >> 6] = m;
    __syncthreads();
    m = fmaxf(fmaxf(redm[0], redm[1]), fmaxf(redm[2], redm[3]));
    float p[4], sum = 0.f;
    #pragma unroll
    for (int c = 0; c < 4; ++c) {
        p[c] = __builtin_amdgcn_exp2f((lg[c] - m) * L2E);
        sum += p[c];
    }
    #pragma unroll
    for (int o = 32; o > 0; o >>= 1) sum += __shfl_xor(sum, o);
    if ((t & 63) == 0) reds[t >> 6] = sum;
    __syncthreads();
    sum = reds[0] + reds[1] + reds[2] + reds[3];
    float inv = __fdividef(1.0f, sum);
    size_t base = (size_t)(b * SEQ + i) * SEQ;
    #pragma unroll
    for (int c = 0; c < 4; ++c) {
        float pv = p[c] * inv;
        u16 h = f2bf(pv);
        p_hi[base + t + c * 256] = h;
        p_lo[base + t + c * 256] = f2bf(pv - bf2f(h));
    }
}

extern "C" void kernel_launch(void* const* d_in, const int* in_sizes, int n_in,
                              void* d_out, int out_size, void* d_ws, size_t ws_size,
                              hipStream_t stream) {
    const float* x  = (const float*)d_in[0];
    const float* Wq = (const float*)d_in[1];
    const float* Wk = (const float*)d_in[2];
    const float* Wv = (const float*)d_in[3];
    const float* W1 = (const float*)d_in[4];
    const float* b1 = (const float*)d_in[5];
    const float* w2 = (const float*)d_in[6];
    // d_in[7] = b2: softmax shift-invariant, unused.

    char* ws = (char*)d_ws;
    float* WcT   = (float*)(ws + 0);          //    65,536 B
    float* A     = (float*)(ws + 65536);      //   262,144 B
    float* Bm    = (float*)(ws + 327680);     //   262,144 B
    u16*   VT_hi = (u16*)(ws + 589824);       // 4,194,304 B (512 x 4096)
    u16*   VT_lo = (u16*)(ws + 4784128);      // 4,194,304 B
    u16*   Xreg  = (u16*)(ws + 8978432);      // 8,388,608 B: x_hi|x_lo, later p_lo
    u16*   Preg  = (u16*)(ws + 17367040);     // 8,388,608 B: wv_hi|wv_lo, later p_hi
    u16* x_hi  = Xreg;
    u16* x_lo  = Xreg + 2097152;
    u16* p_lo  = Xreg;
    u16* wv_hi = Preg;
    u16* wv_lo = Preg + 262144;
    u16* p_hi  = Preg;
    float* out = (float*)d_out;

    hipLaunchKernelGGL(wc_kernel, dim3(32), dim3(256), 0, stream, Wq, Wk, W1, WcT);
    hipLaunchKernelGGL(ab_kernel, dim3(512), dim3(256), 0, stream, x, WcT, b1, A, Bm);
    hipLaunchKernelGGL(split_kernel, dim3(2048), dim3(256), 0, stream, x, x_hi, x_lo, 524288);
    hipLaunchKernelGGL(split_kernel, dim3(256), dim3(256), 0, stream, Wv, wv_hi, wv_lo, 65536);
    // VT[512][4096] = Wv(rows) x x(rows)^T  -> V transposed
    hipLaunchKernelGGL((mfma_gemm<0>), dim3(64, 8, 1), dim3(256), 0, stream,
                       wv_hi, wv_lo, EMBED, x_hi, x_lo, EMBED,
                       8, (size_t)0, (size_t)0, (float*)nullptr, VT_hi, VT_lo, 4096);
    // p (overwrites wv/x regions — stream-ordered after vgemm)
    hipLaunchKernelGGL(attn_kernel, dim3(4096), dim3(256), 0, stream, A, Bm, w2, p_hi, p_lo);
    // out[b*1024+m][n] = sum_k p[b][m][k] * VT[n][b*1024+k]
    hipLaunchKernelGGL((mfma_gemm<1>), dim3(8, 16, 4), dim3(256), 0, stream,
                       p_hi, p_lo, SEQ, VT_hi, VT_lo, 4096,
                       16, (size_t)SEQ * SEQ, (size_t)SEQ, out, (u16*)nullptr, (u16*)nullptr, EMBED);
}